// Round 11
// baseline (283.624 us; speedup 1.0000x reference)
//
#include <hip/hip_runtime.h>
#include <math.h>

#define NH 16          // heads
#define HD 64          // head dim
#define NB 4           // batch
#define SQ 1024        // seq len
#define CH 1024        // channels

typedef __bf16   bf16x8 __attribute__((ext_vector_type(8)));
typedef __bf16   bf16x4 __attribute__((ext_vector_type(4)));
typedef _Float16 f16x8  __attribute__((ext_vector_type(8)));
typedef _Float16 f16x4  __attribute__((ext_vector_type(4)));
typedef float    f32x4  __attribute__((ext_vector_type(4)));

typedef const __attribute__((address_space(1))) void gvoid_t;
typedef __attribute__((address_space(3))) void lvoid_t;

// ---------- split fp32 -> bf16 hi/lo ----------
__global__ __launch_bounds__(256) void k_split(
    const float* __restrict__ in, __bf16* __restrict__ hi,
    __bf16* __restrict__ lo, int n4)
{
    const int idx = blockIdx.x * 256 + threadIdx.x;
    if (idx >= n4) return;
    const float4 v = ((const float4*)in)[idx];
    bf16x4 h, l;
    h[0] = (__bf16)v.x; l[0] = (__bf16)(v.x - (float)h[0]);
    h[1] = (__bf16)v.y; l[1] = (__bf16)(v.y - (float)h[1]);
    h[2] = (__bf16)v.z; l[2] = (__bf16)(v.z - (float)h[2]);
    h[3] = (__bf16)v.w; l[3] = (__bf16)(v.w - (float)h[3]);
    ((bf16x4*)hi)[idx] = h;
    ((bf16x4*)lo)[idx] = l;
}

// ---------- split-bf16 MFMA GEMM: C = A @ B^T (+bias) ----------
template<int EPI>
__global__ __launch_bounds__(256) void k_mfma_gemm(
    const __bf16* __restrict__ Ah, const __bf16* __restrict__ Al,
    const __bf16* __restrict__ Bh, const __bf16* __restrict__ Bl,
    const float* __restrict__ bias, float* __restrict__ outp,
    _Float16* __restrict__ qf, _Float16* __restrict__ kf, _Float16* __restrict__ vTf,
    const float* __restrict__ qg, const float* __restrict__ qb_,
    const float* __restrict__ kg, const float* __restrict__ kb_)
{
    __shared__ __align__(16) __bf16 sAh[128 * 32];
    __shared__ __align__(16) __bf16 sAl[128 * 32];
    __shared__ __align__(16) __bf16 sBh[128 * 32];
    __shared__ __align__(16) __bf16 sBl[128 * 32];

    const int tid = threadIdx.x;
    const int wid = tid >> 6, lane = tid & 63;
    const int wr = wid >> 1, wc = wid & 1;
    const int m0 = blockIdx.y * 128, n0 = blockIdx.x * 128;

    f32x4 acc[4][4];
    #pragma unroll
    for (int i = 0; i < 4; ++i)
        #pragma unroll
        for (int j = 0; j < 4; ++j)
            acc[i][j] = (f32x4){0.f, 0.f, 0.f, 0.f};

    const __bf16* gsrc = (wid == 0) ? Ah : (wid == 1) ? Al : (wid == 2) ? Bh : Bl;
    __bf16* sdst = (wid == 0) ? sAh : (wid == 1) ? sAl : (wid == 2) ? sBh : sBl;
    const int gbase = (wid < 2) ? m0 : n0;
    const int grow = gbase + (lane >> 2);
    const int gcol = (lane & 3) * 8;

    const int arow = wr * 64 + (lane & 15);
    const int brow = wc * 64 + (lane & 15);
    const int koff = (lane >> 4) * 8;

    for (int k0 = 0; k0 < CH; k0 += 32) {
        #pragma unroll
        for (int i = 0; i < 8; ++i) {
            const __bf16* g = gsrc + (size_t)(grow + i * 16) * CH + k0 + gcol;
            __builtin_amdgcn_global_load_lds((gvoid_t*)g,
                                             (lvoid_t*)(sdst + i * 512),
                                             16, 0, 0);
        }
        __syncthreads();

        bf16x8 a_h[4], a_l[4], b_h[4], b_l[4];
        #pragma unroll
        for (int f = 0; f < 4; ++f) {
            a_h[f] = *(const bf16x8*)&sAh[(arow + f * 16) * 32 + koff];
            a_l[f] = *(const bf16x8*)&sAl[(arow + f * 16) * 32 + koff];
            b_h[f] = *(const bf16x8*)&sBh[(brow + f * 16) * 32 + koff];
            b_l[f] = *(const bf16x8*)&sBl[(brow + f * 16) * 32 + koff];
        }
        #pragma unroll
        for (int i = 0; i < 4; ++i)
            #pragma unroll
            for (int j = 0; j < 4; ++j) {
                acc[i][j] = __builtin_amdgcn_mfma_f32_16x16x32_bf16(a_h[i], b_l[j], acc[i][j], 0, 0, 0);
                acc[i][j] = __builtin_amdgcn_mfma_f32_16x16x32_bf16(a_l[i], b_h[j], acc[i][j], 0, 0, 0);
                acc[i][j] = __builtin_amdgcn_mfma_f32_16x16x32_bf16(a_h[i], b_h[j], acc[i][j], 0, 0, 0);
            }
        __syncthreads();
    }

    const int crow = (lane >> 4) * 4;
    const int ccol = lane & 15;

    if (EPI == 1) {
        #pragma unroll
        for (int i = 0; i < 4; ++i) {
            #pragma unroll
            for (int j = 0; j < 4; ++j) {
                const int n = n0 + wc * 64 + j * 16 + ccol;
                const float bv = bias[n];
                #pragma unroll
                for (int r = 0; r < 4; ++r) {
                    const int m = m0 + wr * 64 + i * 16 + crow + r;
                    outp[(size_t)m * CH + n] = acc[i][j][r] + bv;
                }
            }
        }
    } else {
        const int nblk = n0 + wc * 64;
        const int sec = nblk >> 10;           // 0=q 1=k 2=v
        const int h = (nblk & 1023) >> 6;
        float bv[4];
        #pragma unroll
        for (int j = 0; j < 4; ++j) bv[j] = bias[nblk + j * 16 + ccol];

        if (sec < 2) {
            const float* gp = (sec == 0) ? qg : kg;
            const float* bp = (sec == 0) ? qb_ : kb_;
            float g4[4], b4[4];
            #pragma unroll
            for (int j = 0; j < 4; ++j) { g4[j] = gp[j*16+ccol]; b4[j] = bp[j*16+ccol]; }
            const float scale = (sec == 0) ? 0.125f : 1.0f;
            _Float16* dst = (sec == 0) ? qf : kf;
            #pragma unroll
            for (int i = 0; i < 4; ++i) {
                #pragma unroll
                for (int r = 0; r < 4; ++r) {
                    const int m = m0 + wr * 64 + i * 16 + crow + r;
                    const int b_ = m >> 10, nn = m & 1023;
                    float vals[4], s = 0.f, q2 = 0.f;
                    #pragma unroll
                    for (int j = 0; j < 4; ++j) {
                        vals[j] = acc[i][j][r] + bv[j];
                        s += vals[j]; q2 += vals[j] * vals[j];
                    }
                    #pragma unroll
                    for (int o = 1; o < 16; o <<= 1) {
                        s  += __shfl_xor(s, o, 64);
                        q2 += __shfl_xor(q2, o, 64);
                    }
                    const float mean = s * 0.015625f;
                    const float var = q2 * 0.015625f - mean * mean;
                    const float rstd = rsqrtf(var + 1e-5f);
                    #pragma unroll
                    for (int j = 0; j < 4; ++j) {
                        const float y = ((vals[j] - mean) * rstd * g4[j] + b4[j]) * scale;
                        dst[((size_t)(b_ * NH + h) * SQ + nn) * HD + j * 16 + ccol] = (_Float16)y;
                    }
                }
            }
        } else {
            #pragma unroll
            for (int i = 0; i < 4; ++i) {
                const int m0r = m0 + wr * 64 + i * 16 + crow;
                const int b_ = m0r >> 10, nn0 = m0r & 1023;
                #pragma unroll
                for (int j = 0; j < 4; ++j) {
                    f16x4 tmp;
                    #pragma unroll
                    for (int r = 0; r < 4; ++r) tmp[r] = (_Float16)(acc[i][j][r] + bv[j]);
                    *(f16x4*)&vTf[((size_t)(b_ * NH + h) * HD + j * 16 + ccol) * SQ + nn0] = tmp;
                }
            }
        }
    }
}

// ---------- fused QK^T + softmax(no-max: |logit|<=8 rigorous) + weights + PV ----------
// 32 q-rows per wave; swapped-operand QK^T; plain f32x4 weight stores; XCD
// clustering. Phase 2: 1-deep register prefetch of K/V issued BEFORE the
// W stores — in-order vmcnt completion means loads issued after stores would
// inherit store-ack latency; prefetching decouples them by a full iteration.
__global__ __launch_bounds__(256) void k_attn(
    const _Float16* __restrict__ q, const _Float16* __restrict__ k,
    const _Float16* __restrict__ vT, float* __restrict__ W,
    float* __restrict__ op)
{
    __shared__ _Float16 Pl[4][32][40];   // padded rows (80B): no 8-way conflicts
    const int L = blockIdx.x;            // 512 blocks
    const int bh   = (L & 7) * 8 + (L >> 6);
    const int xblk = (L >> 3) & 7;
    const int wid = threadIdx.x >> 6, lane = threadIdx.x & 63;
    const int row0 = xblk * 128 + wid * 32;   // this wave's 32 q-rows
    const int lr = lane & 15, lg = lane >> 4;

    const _Float16* qh = q  + (size_t)bh * SQ * HD;
    const _Float16* kh = k  + (size_t)bh * SQ * HD;
    const _Float16* vh = vT + (size_t)bh * HD * SQ;

    // Q B-fragments: qb[qf][c] covers q-rows row0+qf*16, d-chunk c*32
    f16x8 qb[2][2];
    #pragma unroll
    for (int qf = 0; qf < 2; ++qf)
        #pragma unroll
        for (int c = 0; c < 2; ++c)
            qb[qf][c] = *(const f16x8*)&qh[(size_t)(row0 + qf * 16 + lr) * HD + c * 32 + lg * 8];

    // ---- phase 1: per-q row sums of exp(s) ----
    float lp0 = 0.f, lp1 = 0.f;
    #pragma unroll 4
    for (int kt = 0; kt < 64; ++kt) {
        const f16x8 ka0 = *(const f16x8*)&kh[(size_t)(kt * 16 + lr) * HD + lg * 8];
        const f16x8 ka1 = *(const f16x8*)&kh[(size_t)(kt * 16 + lr) * HD + 32 + lg * 8];
        f32x4 s0 = (f32x4){0.f, 0.f, 0.f, 0.f};
        f32x4 s1 = (f32x4){0.f, 0.f, 0.f, 0.f};
        s0 = __builtin_amdgcn_mfma_f32_16x16x32_f16(ka0, qb[0][0], s0, 0, 0, 0);
        s0 = __builtin_amdgcn_mfma_f32_16x16x32_f16(ka1, qb[0][1], s0, 0, 0, 0);
        s1 = __builtin_amdgcn_mfma_f32_16x16x32_f16(ka0, qb[1][0], s1, 0, 0, 0);
        s1 = __builtin_amdgcn_mfma_f32_16x16x32_f16(ka1, qb[1][1], s1, 0, 0, 0);
        #pragma unroll
        for (int r = 0; r < 4; ++r) { lp0 += __expf(s0[r]); lp1 += __expf(s1[r]); }
    }
    lp0 += __shfl_xor(lp0, 16, 64); lp0 += __shfl_xor(lp0, 32, 64);
    lp1 += __shfl_xor(lp1, 16, 64); lp1 += __shfl_xor(lp1, 32, 64);
    const float invl0 = 1.0f / lp0;      // q = row0 + lr
    const float invl1 = 1.0f / lp1;      // q = row0 + 16 + lr

    // ---- phase 2: register-prefetched pipeline ----
    float* Wr = W + (size_t)bh * SQ * SQ;
    f32x4 opv[4][2];
    #pragma unroll
    for (int dt = 0; dt < 4; ++dt)
        #pragma unroll
        for (int qf = 0; qf < 2; ++qf)
            opv[dt][qf] = (f32x4){0.f, 0.f, 0.f, 0.f};

    // preload jc=0 K (4 frags) and V (4 frags)
    f16x8 kc0[2], kc1[2], vc[4];
    #pragma unroll
    for (int t = 0; t < 2; ++t) {
        kc0[t] = *(const f16x8*)&kh[(size_t)(t * 16 + lr) * HD + lg * 8];
        kc1[t] = *(const f16x8*)&kh[(size_t)(t * 16 + lr) * HD + 32 + lg * 8];
    }
    #pragma unroll
    for (int dt = 0; dt < 4; ++dt)
        vc[dt] = *(const f16x8*)&vh[(size_t)(dt * 16 + lr) * SQ + lg * 8];

    for (int jc = 0; jc < 32; ++jc) {          // 32-k chunks
        // S for both sub-tiles from register K (reg-to-reg MFMA)
        f32x4 s[2][2];   // [t][qf]
        #pragma unroll
        for (int t = 0; t < 2; ++t) {
            s[t][0] = (f32x4){0.f, 0.f, 0.f, 0.f};
            s[t][1] = (f32x4){0.f, 0.f, 0.f, 0.f};
            s[t][0] = __builtin_amdgcn_mfma_f32_16x16x32_f16(kc0[t], qb[0][0], s[t][0], 0, 0, 0);
            s[t][0] = __builtin_amdgcn_mfma_f32_16x16x32_f16(kc1[t], qb[0][1], s[t][0], 0, 0, 0);
            s[t][1] = __builtin_amdgcn_mfma_f32_16x16x32_f16(kc0[t], qb[1][0], s[t][1], 0, 0, 0);
            s[t][1] = __builtin_amdgcn_mfma_f32_16x16x32_f16(kc1[t], qb[1][1], s[t][1], 0, 0, 0);
        }

        // PREFETCH jc+1 (wrap-indexed: unconditional) — issued BEFORE stores
        const int jn = (jc + 1) & 31;
        f16x8 kn0[2], kn1[2], vn[4];
        #pragma unroll
        for (int t = 0; t < 2; ++t) {
            const int kt = jn * 2 + t;
            kn0[t] = *(const f16x8*)&kh[(size_t)(kt * 16 + lr) * HD + lg * 8];
            kn1[t] = *(const f16x8*)&kh[(size_t)(kt * 16 + lr) * HD + 32 + lg * 8];
        }
        #pragma unroll
        for (int dt = 0; dt < 4; ++dt)
            vn[dt] = *(const f16x8*)&vh[(size_t)(dt * 16 + lr) * SQ + jn * 32 + lg * 8];

        // softmax-normalize, store W, stage P in LDS
        #pragma unroll
        for (int t = 0; t < 2; ++t) {
            const int kt = jc * 2 + t;
            f32x4 wv0, wv1;
            f16x4 pv0, pv1;
            #pragma unroll
            for (int r = 0; r < 4; ++r) {
                wv0[r] = __expf(s[t][0][r]) * invl0;  pv0[r] = (_Float16)wv0[r];
                wv1[r] = __expf(s[t][1][r]) * invl1;  pv1[r] = (_Float16)wv1[r];
            }
            *(f32x4*)&Wr[(size_t)(row0 + lr) * SQ + kt * 16 + lg * 4]      = wv0;
            *(f32x4*)&Wr[(size_t)(row0 + 16 + lr) * SQ + kt * 16 + lg * 4] = wv1;
            *(f16x4*)&Pl[wid][lr][t * 16 + lg * 4]      = pv0;
            *(f16x4*)&Pl[wid][16 + lr][t * 16 + lg * 4] = pv1;
        }
        const f16x8 pa0 = *(const f16x8*)&Pl[wid][lr][lg * 8];
        const f16x8 pa1 = *(const f16x8*)&Pl[wid][16 + lr][lg * 8];
        #pragma unroll
        for (int dt = 0; dt < 4; ++dt) {
            opv[dt][0] = __builtin_amdgcn_mfma_f32_16x16x32_f16(pa0, vc[dt], opv[dt][0], 0, 0, 0);
            opv[dt][1] = __builtin_amdgcn_mfma_f32_16x16x32_f16(pa1, vc[dt], opv[dt][1], 0, 0, 0);
        }

        // rotate prefetched registers
        #pragma unroll
        for (int t = 0; t < 2; ++t) { kc0[t] = kn0[t]; kc1[t] = kn1[t]; }
        #pragma unroll
        for (int dt = 0; dt < 4; ++dt) vc[dt] = vn[dt];
    }

    // epilogue: write attention output as f32 [B,N,C] (split pass makes hi/lo)
    const int b_ = bh >> 4, h = bh & 15;
    #pragma unroll
    for (int dt = 0; dt < 4; ++dt)
        #pragma unroll
        for (int qf = 0; qf < 2; ++qf)
            #pragma unroll
            for (int r = 0; r < 4; ++r) {
                const int row = row0 + qf * 16 + lg * 4 + r;
                op[((size_t)(b_ * SQ + row)) * CH + h * HD + dt * 16 + lr] = opv[dt][qf][r];
            }
}

extern "C" void kernel_launch(void* const* d_in, const int* in_sizes, int n_in,
                              void* d_out, int out_size, void* d_ws, size_t ws_size,
                              hipStream_t stream)
{
    const float* x    = (const float*)d_in[0];
    const float* Wqkv = (const float*)d_in[1];
    const float* bqkv = (const float*)d_in[2];
    const float* qg   = (const float*)d_in[3];
    const float* qb   = (const float*)d_in[4];
    const float* kg   = (const float*)d_in[5];
    const float* kb   = (const float*)d_in[6];
    const float* Wp   = (const float*)d_in[7];
    const float* bp   = (const float*)d_in[8];

    float* out     = (float*)d_out;                       // [B,N,C]
    float* weights = out + (size_t)NB * SQ * CH;          // [B,H,N,N]

    // ws layout (MB): xh 0-8, xl 8-16, wqh 16-22, wql 22-28, wph 28-30, wpl 30-32,
    //                 qf 32-40, kf 40-48, vT 48-56, oph 56-64, opl 64-72
    // after QKV GEMM xh/xl are dead -> op (f32, 16MB) aliases 0-16
    char* w = (char*)d_ws;
    __bf16*   xh  = (__bf16*)w;
    __bf16*   xl  = (__bf16*)(w + (((size_t)8)  << 20));
    __bf16*   wqh = (__bf16*)(w + (((size_t)16) << 20));
    __bf16*   wql = (__bf16*)(w + (((size_t)22) << 20));
    __bf16*   wph = (__bf16*)(w + (((size_t)28) << 20));
    __bf16*   wpl = (__bf16*)(w + (((size_t)30) << 20));
    _Float16* qf  = (_Float16*)(w + (((size_t)32) << 20));
    _Float16* kf  = (_Float16*)(w + (((size_t)40) << 20));
    _Float16* vTf = (_Float16*)(w + (((size_t)48) << 20));
    __bf16*   oph = (__bf16*)(w + (((size_t)56) << 20));
    __bf16*   opl = (__bf16*)(w + (((size_t)64) << 20));
    float*    op  = (float*)w;                            // alias xh/xl

    // 0) split fp32 inputs to bf16 hi/lo
    k_split<<<(NB*SQ*CH/4 + 255)/256, 256, 0, stream>>>(x, xh, xl, NB*SQ*CH/4);
    k_split<<<(3*CH*CH/4 + 255)/256, 256, 0, stream>>>(Wqkv, wqh, wql, 3*CH*CH/4);
    k_split<<<(CH*CH/4 + 255)/256, 256, 0, stream>>>(Wp, wph, wpl, CH*CH/4);

    // 1) qkv GEMM + fused bias+LN epilogue -> q,k fp16 (LN'd), vT fp16
    k_mfma_gemm<0><<<dim3(24, 32), 256, 0, stream>>>(
        xh, xl, wqh, wql, bqkv, nullptr, qf, kf, vTf, qg, qb, kg, kb);

    // 2) fused attention: QK^T + exact softmax + weights write + PV (f32 out)
    k_attn<<<dim3(512), 256, 0, stream>>>(qf, kf, vTf, weights, op);

    // 2b) split attention output to bf16 hi/lo for proj
    k_split<<<dim3(NB*SQ*CH/4/256), 256, 0, stream>>>(op, oph, opl, NB*SQ*CH/4);

    // 3) proj GEMM
    k_mfma_gemm<1><<<dim3(8, 32), 256, 0, stream>>>(
        oph, opl, wph, wpl, bp, out, nullptr, nullptr, nullptr,
        nullptr, nullptr, nullptr, nullptr);
}

// Round 12
// 258.407 us; speedup vs baseline: 1.0976x; 1.0976x over previous
//
#include <hip/hip_runtime.h>
#include <math.h>

#define NH 16          // heads
#define HD 64          // head dim
#define NB 4           // batch
#define SQ 1024        // seq len
#define CH 1024        // channels

typedef __bf16   bf16x8 __attribute__((ext_vector_type(8)));
typedef __bf16   bf16x4 __attribute__((ext_vector_type(4)));
typedef _Float16 f16x8  __attribute__((ext_vector_type(8)));
typedef _Float16 f16x4  __attribute__((ext_vector_type(4)));
typedef float    f32x4  __attribute__((ext_vector_type(4)));

typedef const __attribute__((address_space(1))) void gvoid_t;
typedef __attribute__((address_space(3))) void lvoid_t;

// ---------- split fp32 -> bf16 hi/lo ----------
__global__ __launch_bounds__(256) void k_split(
    const float* __restrict__ in, __bf16* __restrict__ hi,
    __bf16* __restrict__ lo, int n4)
{
    const int idx = blockIdx.x * 256 + threadIdx.x;
    if (idx >= n4) return;
    const float4 v = ((const float4*)in)[idx];
    bf16x4 h, l;
    h[0] = (__bf16)v.x; l[0] = (__bf16)(v.x - (float)h[0]);
    h[1] = (__bf16)v.y; l[1] = (__bf16)(v.y - (float)h[1]);
    h[2] = (__bf16)v.z; l[2] = (__bf16)(v.z - (float)h[2]);
    h[3] = (__bf16)v.w; l[3] = (__bf16)(v.w - (float)h[3]);
    ((bf16x4*)hi)[idx] = h;
    ((bf16x4*)lo)[idx] = l;
}

// ---------- hi-only split (for x: 2-pass QKV GEMM needs no A_lo) ----------
__global__ __launch_bounds__(256) void k_split_hi(
    const float* __restrict__ in, __bf16* __restrict__ hi, int n4)
{
    const int idx = blockIdx.x * 256 + threadIdx.x;
    if (idx >= n4) return;
    const float4 v = ((const float4*)in)[idx];
    bf16x4 h;
    h[0] = (__bf16)v.x; h[1] = (__bf16)v.y;
    h[2] = (__bf16)v.z; h[3] = (__bf16)v.w;
    ((bf16x4*)hi)[idx] = h;
}

// ---------- split-bf16 MFMA GEMM: C = A @ B^T (+bias) ----------
// PASSES==3: acc += Ah*Bl + Al*Bh + Ah*Bh   (full split)
// PASSES==2: acc += Ah*Bl + Ah*Bh           (drop Al term; Al not staged)
template<int EPI, int PASSES>
__global__ __launch_bounds__(256) void k_mfma_gemm(
    const __bf16* __restrict__ Ah, const __bf16* __restrict__ Al,
    const __bf16* __restrict__ Bh, const __bf16* __restrict__ Bl,
    const float* __restrict__ bias, float* __restrict__ outp,
    _Float16* __restrict__ qf, _Float16* __restrict__ kf, _Float16* __restrict__ vTf,
    const float* __restrict__ qg, const float* __restrict__ qb_,
    const float* __restrict__ kg, const float* __restrict__ kb_)
{
    __shared__ __align__(16) __bf16 sAh[128 * 32];
    __shared__ __align__(16) __bf16 sAl[(PASSES == 3) ? 128 * 32 : 8];
    __shared__ __align__(16) __bf16 sBh[128 * 32];
    __shared__ __align__(16) __bf16 sBl[128 * 32];

    const int tid = threadIdx.x;
    const int wid = tid >> 6, lane = tid & 63;
    const int wr = wid >> 1, wc = wid & 1;
    const int m0 = blockIdx.y * 128, n0 = blockIdx.x * 128;

    f32x4 acc[4][4];
    #pragma unroll
    for (int i = 0; i < 4; ++i)
        #pragma unroll
        for (int j = 0; j < 4; ++j)
            acc[i][j] = (f32x4){0.f, 0.f, 0.f, 0.f};

    // staging assignment
    const __bf16* gsrc;
    __bf16* sdst;
    int nloads, ibase, gbase;
    if (PASSES == 3) {
        gsrc = (wid == 0) ? Ah : (wid == 1) ? Al : (wid == 2) ? Bh : Bl;
        sdst = (wid == 0) ? sAh : (wid == 1) ? sAl : (wid == 2) ? sBh : sBl;
        gbase = (wid < 2) ? m0 : n0;
        nloads = 8; ibase = 0;
    } else {
        // wid0: Ah rows 0-63, wid3: Ah rows 64-127, wid1: Bh, wid2: Bl
        gsrc = (wid == 1) ? Bh : (wid == 2) ? Bl : Ah;
        sdst = (wid == 1) ? sBh : (wid == 2) ? sBl : sAh;
        gbase = (wid == 1 || wid == 2) ? n0 : m0;
        nloads = (wid == 1 || wid == 2) ? 8 : 4;
        ibase = (wid == 3) ? 4 : 0;
    }
    const int grow = gbase + (lane >> 2);
    const int gcol = (lane & 3) * 8;

    const int arow = wr * 64 + (lane & 15);
    const int brow = wc * 64 + (lane & 15);
    const int koff = (lane >> 4) * 8;

    for (int k0 = 0; k0 < CH; k0 += 32) {
        for (int i = 0; i < nloads; ++i) {
            const __bf16* g = gsrc + (size_t)(grow + (ibase + i) * 16) * CH + k0 + gcol;
            __builtin_amdgcn_global_load_lds((gvoid_t*)g,
                                             (lvoid_t*)(sdst + (ibase + i) * 512),
                                             16, 0, 0);
        }
        __syncthreads();

        bf16x8 a_h[4], b_h[4], b_l[4];
        bf16x8 a_l[4];
        #pragma unroll
        for (int f = 0; f < 4; ++f) {
            a_h[f] = *(const bf16x8*)&sAh[(arow + f * 16) * 32 + koff];
            b_h[f] = *(const bf16x8*)&sBh[(brow + f * 16) * 32 + koff];
            b_l[f] = *(const bf16x8*)&sBl[(brow + f * 16) * 32 + koff];
            if (PASSES == 3)
                a_l[f] = *(const bf16x8*)&sAl[(arow + f * 16) * 32 + koff];
        }
        #pragma unroll
        for (int i = 0; i < 4; ++i)
            #pragma unroll
            for (int j = 0; j < 4; ++j) {
                acc[i][j] = __builtin_amdgcn_mfma_f32_16x16x32_bf16(a_h[i], b_l[j], acc[i][j], 0, 0, 0);
                if (PASSES == 3)
                    acc[i][j] = __builtin_amdgcn_mfma_f32_16x16x32_bf16(a_l[i], b_h[j], acc[i][j], 0, 0, 0);
                acc[i][j] = __builtin_amdgcn_mfma_f32_16x16x32_bf16(a_h[i], b_h[j], acc[i][j], 0, 0, 0);
            }
        __syncthreads();
    }

    const int crow = (lane >> 4) * 4;
    const int ccol = lane & 15;

    if (EPI == 1) {
        #pragma unroll
        for (int i = 0; i < 4; ++i) {
            #pragma unroll
            for (int j = 0; j < 4; ++j) {
                const int n = n0 + wc * 64 + j * 16 + ccol;
                const float bv = bias[n];
                #pragma unroll
                for (int r = 0; r < 4; ++r) {
                    const int m = m0 + wr * 64 + i * 16 + crow + r;
                    outp[(size_t)m * CH + n] = acc[i][j][r] + bv;
                }
            }
        }
    } else {
        const int nblk = n0 + wc * 64;
        const int sec = nblk >> 10;           // 0=q 1=k 2=v
        const int h = (nblk & 1023) >> 6;
        float bv[4];
        #pragma unroll
        for (int j = 0; j < 4; ++j) bv[j] = bias[nblk + j * 16 + ccol];

        if (sec < 2) {
            const float* gp = (sec == 0) ? qg : kg;
            const float* bp = (sec == 0) ? qb_ : kb_;
            float g4[4], b4[4];
            #pragma unroll
            for (int j = 0; j < 4; ++j) { g4[j] = gp[j*16+ccol]; b4[j] = bp[j*16+ccol]; }
            const float scale = (sec == 0) ? 0.125f : 1.0f;
            _Float16* dst = (sec == 0) ? qf : kf;
            #pragma unroll
            for (int i = 0; i < 4; ++i) {
                #pragma unroll
                for (int r = 0; r < 4; ++r) {
                    const int m = m0 + wr * 64 + i * 16 + crow + r;
                    const int b_ = m >> 10, nn = m & 1023;
                    float vals[4], s = 0.f, q2 = 0.f;
                    #pragma unroll
                    for (int j = 0; j < 4; ++j) {
                        vals[j] = acc[i][j][r] + bv[j];
                        s += vals[j]; q2 += vals[j] * vals[j];
                    }
                    #pragma unroll
                    for (int o = 1; o < 16; o <<= 1) {
                        s  += __shfl_xor(s, o, 64);
                        q2 += __shfl_xor(q2, o, 64);
                    }
                    const float mean = s * 0.015625f;
                    const float var = q2 * 0.015625f - mean * mean;
                    const float rstd = rsqrtf(var + 1e-5f);
                    #pragma unroll
                    for (int j = 0; j < 4; ++j) {
                        const float y = ((vals[j] - mean) * rstd * g4[j] + b4[j]) * scale;
                        dst[((size_t)(b_ * NH + h) * SQ + nn) * HD + j * 16 + ccol] = (_Float16)y;
                    }
                }
            }
        } else {
            #pragma unroll
            for (int i = 0; i < 4; ++i) {
                const int m0r = m0 + wr * 64 + i * 16 + crow;
                const int b_ = m0r >> 10, nn0 = m0r & 1023;
                #pragma unroll
                for (int j = 0; j < 4; ++j) {
                    f16x4 tmp;
                    #pragma unroll
                    for (int r = 0; r < 4; ++r) tmp[r] = (_Float16)(acc[i][j][r] + bv[j]);
                    *(f16x4*)&vTf[((size_t)(b_ * NH + h) * HD + j * 16 + ccol) * SQ + nn0] = tmp;
                }
            }
        }
    }
}

// ---------- fused QK^T + softmax(no-max: |logit|<=8 rigorous) + weights + PV ----------
// R10 structure: 32 q-rows/wave, swapped-operand QK^T, plain f32x4 W stores,
// XCD clustering, V loads issued before stores each iteration.
__global__ __launch_bounds__(256) void k_attn(
    const _Float16* __restrict__ q, const _Float16* __restrict__ k,
    const _Float16* __restrict__ vT, float* __restrict__ W,
    float* __restrict__ op)
{
    __shared__ _Float16 Pl[4][32][40];   // padded rows (80B): no 8-way conflicts
    const int L = blockIdx.x;            // 512 blocks
    const int bh   = (L & 7) * 8 + (L >> 6);
    const int xblk = (L >> 3) & 7;
    const int wid = threadIdx.x >> 6, lane = threadIdx.x & 63;
    const int row0 = xblk * 128 + wid * 32;   // this wave's 32 q-rows
    const int lr = lane & 15, lg = lane >> 4;

    const _Float16* qh = q  + (size_t)bh * SQ * HD;
    const _Float16* kh = k  + (size_t)bh * SQ * HD;
    const _Float16* vh = vT + (size_t)bh * HD * SQ;

    f16x8 qb[2][2];
    #pragma unroll
    for (int qf = 0; qf < 2; ++qf)
        #pragma unroll
        for (int c = 0; c < 2; ++c)
            qb[qf][c] = *(const f16x8*)&qh[(size_t)(row0 + qf * 16 + lr) * HD + c * 32 + lg * 8];

    // ---- phase 1: per-q row sums of exp(s) ----
    float lp0 = 0.f, lp1 = 0.f;
    #pragma unroll 4
    for (int kt = 0; kt < 64; ++kt) {
        const f16x8 ka0 = *(const f16x8*)&kh[(size_t)(kt * 16 + lr) * HD + lg * 8];
        const f16x8 ka1 = *(const f16x8*)&kh[(size_t)(kt * 16 + lr) * HD + 32 + lg * 8];
        f32x4 s0 = (f32x4){0.f, 0.f, 0.f, 0.f};
        f32x4 s1 = (f32x4){0.f, 0.f, 0.f, 0.f};
        s0 = __builtin_amdgcn_mfma_f32_16x16x32_f16(ka0, qb[0][0], s0, 0, 0, 0);
        s0 = __builtin_amdgcn_mfma_f32_16x16x32_f16(ka1, qb[0][1], s0, 0, 0, 0);
        s1 = __builtin_amdgcn_mfma_f32_16x16x32_f16(ka0, qb[1][0], s1, 0, 0, 0);
        s1 = __builtin_amdgcn_mfma_f32_16x16x32_f16(ka1, qb[1][1], s1, 0, 0, 0);
        #pragma unroll
        for (int r = 0; r < 4; ++r) { lp0 += __expf(s0[r]); lp1 += __expf(s1[r]); }
    }
    lp0 += __shfl_xor(lp0, 16, 64); lp0 += __shfl_xor(lp0, 32, 64);
    lp1 += __shfl_xor(lp1, 16, 64); lp1 += __shfl_xor(lp1, 32, 64);
    const float invl0 = 1.0f / lp0;      // q = row0 + lr
    const float invl1 = 1.0f / lp1;      // q = row0 + 16 + lr

    // ---- phase 2: recompute s, write weights (plain f32x4), PV ----
    float* Wr = W + (size_t)bh * SQ * SQ;
    f32x4 opv[4][2];
    #pragma unroll
    for (int dt = 0; dt < 4; ++dt)
        #pragma unroll
        for (int qf = 0; qf < 2; ++qf)
            opv[dt][qf] = (f32x4){0.f, 0.f, 0.f, 0.f};

    for (int jc = 0; jc < 32; ++jc) {          // 32-k chunks
        // V loads first — independent of P, free to fly early
        f16x8 vb[4];
        #pragma unroll
        for (int dt = 0; dt < 4; ++dt)
            vb[dt] = *(const f16x8*)&vh[(size_t)(dt * 16 + lr) * SQ + jc * 32 + lg * 8];

        #pragma unroll
        for (int t = 0; t < 2; ++t) {
            const int kt = jc * 2 + t;
            const f16x8 ka0 = *(const f16x8*)&kh[(size_t)(kt * 16 + lr) * HD + lg * 8];
            const f16x8 ka1 = *(const f16x8*)&kh[(size_t)(kt * 16 + lr) * HD + 32 + lg * 8];
            f32x4 s0 = (f32x4){0.f, 0.f, 0.f, 0.f};
            f32x4 s1 = (f32x4){0.f, 0.f, 0.f, 0.f};
            s0 = __builtin_amdgcn_mfma_f32_16x16x32_f16(ka0, qb[0][0], s0, 0, 0, 0);
            s0 = __builtin_amdgcn_mfma_f32_16x16x32_f16(ka1, qb[0][1], s0, 0, 0, 0);
            s1 = __builtin_amdgcn_mfma_f32_16x16x32_f16(ka0, qb[1][0], s1, 0, 0, 0);
            s1 = __builtin_amdgcn_mfma_f32_16x16x32_f16(ka1, qb[1][1], s1, 0, 0, 0);
            f32x4 wv0, wv1;
            f16x4 pv0, pv1;
            #pragma unroll
            for (int r = 0; r < 4; ++r) {
                wv0[r] = __expf(s0[r]) * invl0;  pv0[r] = (_Float16)wv0[r];
                wv1[r] = __expf(s1[r]) * invl1;  pv1[r] = (_Float16)wv1[r];
            }
            *(f32x4*)&Wr[(size_t)(row0 + lr) * SQ + kt * 16 + lg * 4]      = wv0;
            *(f32x4*)&Wr[(size_t)(row0 + 16 + lr) * SQ + kt * 16 + lg * 4] = wv1;
            *(f16x4*)&Pl[wid][lr][t * 16 + lg * 4]      = pv0;
            *(f16x4*)&Pl[wid][16 + lr][t * 16 + lg * 4] = pv1;
        }
        const f16x8 pa0 = *(const f16x8*)&Pl[wid][lr][lg * 8];
        const f16x8 pa1 = *(const f16x8*)&Pl[wid][16 + lr][lg * 8];
        #pragma unroll
        for (int dt = 0; dt < 4; ++dt) {
            opv[dt][0] = __builtin_amdgcn_mfma_f32_16x16x32_f16(pa0, vb[dt], opv[dt][0], 0, 0, 0);
            opv[dt][1] = __builtin_amdgcn_mfma_f32_16x16x32_f16(pa1, vb[dt], opv[dt][1], 0, 0, 0);
        }
    }

    // epilogue: write attention output as f32 [B,N,C] (split pass makes hi/lo)
    const int b_ = bh >> 4, h = bh & 15;
    #pragma unroll
    for (int dt = 0; dt < 4; ++dt)
        #pragma unroll
        for (int qf = 0; qf < 2; ++qf)
            #pragma unroll
            for (int r = 0; r < 4; ++r) {
                const int row = row0 + qf * 16 + lg * 4 + r;
                op[((size_t)(b_ * SQ + row)) * CH + h * HD + dt * 16 + lr] = opv[dt][qf][r];
            }
}

extern "C" void kernel_launch(void* const* d_in, const int* in_sizes, int n_in,
                              void* d_out, int out_size, void* d_ws, size_t ws_size,
                              hipStream_t stream)
{
    const float* x    = (const float*)d_in[0];
    const float* Wqkv = (const float*)d_in[1];
    const float* bqkv = (const float*)d_in[2];
    const float* qg   = (const float*)d_in[3];
    const float* qb   = (const float*)d_in[4];
    const float* kg   = (const float*)d_in[5];
    const float* kb   = (const float*)d_in[6];
    const float* Wp   = (const float*)d_in[7];
    const float* bp   = (const float*)d_in[8];

    float* out     = (float*)d_out;                       // [B,N,C]
    float* weights = out + (size_t)NB * SQ * CH;          // [B,H,N,N]

    // ws layout (MB): xh 0-8, (8-16 free), wqh 16-22, wql 22-28, wph 28-30,
    //                 wpl 30-32, qf 32-40, kf 40-48, vT 48-56, oph 56-64,
    //                 opl 64-72.  op (f32 16MB) aliases 0-16 after QKV GEMM.
    char* w = (char*)d_ws;
    __bf16*   xh  = (__bf16*)w;
    __bf16*   wqh = (__bf16*)(w + (((size_t)16) << 20));
    __bf16*   wql = (__bf16*)(w + (((size_t)22) << 20));
    __bf16*   wph = (__bf16*)(w + (((size_t)28) << 20));
    __bf16*   wpl = (__bf16*)(w + (((size_t)30) << 20));
    _Float16* qf  = (_Float16*)(w + (((size_t)32) << 20));
    _Float16* kf  = (_Float16*)(w + (((size_t)40) << 20));
    _Float16* vTf = (_Float16*)(w + (((size_t)48) << 20));
    __bf16*   oph = (__bf16*)(w + (((size_t)56) << 20));
    __bf16*   opl = (__bf16*)(w + (((size_t)64) << 20));
    float*    op  = (float*)w;                            // alias xh (x dead)

    // 0) splits: x hi-only (2-pass QKV), weights full hi/lo
    k_split_hi<<<(NB*SQ*CH/4 + 255)/256, 256, 0, stream>>>(x, xh, NB*SQ*CH/4);
    k_split<<<(3*CH*CH/4 + 255)/256, 256, 0, stream>>>(Wqkv, wqh, wql, 3*CH*CH/4);
    k_split<<<(CH*CH/4 + 255)/256, 256, 0, stream>>>(Wp, wph, wpl, CH*CH/4);

    // 1) qkv GEMM (2-pass) + fused bias+LN epilogue -> q,k fp16 (LN'd), vT fp16
    k_mfma_gemm<0, 2><<<dim3(24, 32), 256, 0, stream>>>(
        xh, nullptr, wqh, wql, bqkv, nullptr, qf, kf, vTf, qg, qb, kg, kb);

    // 2) fused attention: QK^T + exact softmax + weights write + PV (f32 out)
    k_attn<<<dim3(512), 256, 0, stream>>>(qf, kf, vTf, weights, op);

    // 2b) split attention output to bf16 hi/lo for proj
    k_split<<<dim3(NB*SQ*CH/4/256), 256, 0, stream>>>(op, oph, opl, NB*SQ*CH/4);

    // 3) proj GEMM (3-pass: keep v->out path accurate)
    k_mfma_gemm<1, 3><<<dim3(8, 32), 256, 0, stream>>>(
        oph, opl, wph, wpl, bp, out, nullptr, nullptr, nullptr,
        nullptr, nullptr, nullptr, nullptr);
}